// Round 17
// baseline (576.448 us; speedup 1.0000x reference)
//
#include <hip/hip_runtime.h>
#include <cstdint>
#include <cstddef>
#include <cmath>

// ---- problem constants ----
#define B_  4
#define S_  2048
#define DM_ 1024
#define H_  16

typedef _Float16 h8 __attribute__((ext_vector_type(8)));
typedef _Float16 h4 __attribute__((ext_vector_type(4)));
typedef float f32x4 __attribute__((ext_vector_type(4)));

#define MFMA16(A_, B2_, C_) __builtin_amdgcn_mfma_f32_16x16x32_f16((A_), (B2_), (C_), 0, 0, 0)

// exp2 folding: p = exp2(a * (0.125*log2e) + bias2), bias2 = bias*log2e (fp16 rounding
// of bias2 cancels exactly between qk1's denominator and qk2's numerator).
#define C_EXP2 0.18033688011112042f
#define BIAS2_UNMASKED -14.426950408889634f
#define BIAS2_MASKED   -60000.0f

__device__ __forceinline__ void gload_lds16(const void* g, void* l) {
  __builtin_amdgcn_global_load_lds(
      (const __attribute__((address_space(1))) unsigned int*)g,
      (__attribute__((address_space(3))) unsigned int*)l, 16, 0, 0);
}

// ---------------- fp32 -> fp16 convert (proven round-0 pattern) ----------------
__global__ __launch_bounds__(256) void cvt_kernel(const float* __restrict__ in,
                                                  _Float16* __restrict__ out, int n4) {
  int i = blockIdx.x * 256 + threadIdx.x;
  if (i < n4) {
    f32x4 v = ((const f32x4*)in)[i];
    h4 o;
    o[0] = (_Float16)v[0]; o[1] = (_Float16)v[1];
    o[2] = (_Float16)v[2]; o[3] = (_Float16)v[3];
    ((h4*)out)[i] = o;
  }
}

// ---------------- GEMM: C[m,n] = sum_k A[m,k] * W[n,k] ----------------
template <int MODE, int A16>
__global__ __launch_bounds__(256, 2)
void gemm_bt(const void* __restrict__ Ap, const void* __restrict__ Wp,
             void* __restrict__ outp, int M, int N, int K) {
  __shared__ _Float16 As[128 * 32];
  __shared__ _Float16 Bs[128 * 32];
  const int tid = threadIdx.x;
  const int w = tid >> 6, lane = tid & 63;
  const int g = lane >> 4, li = lane & 15;
  const int wr = w >> 1, wc = w & 1;
  const int mBase = blockIdx.y * 128, nBase = blockIdx.x * 128;

  f32x4 acc[4][4] = {};

  _Float16* lA = As + w * 1024;
  _Float16* lB = Bs + w * 1024;

  const _Float16* gA16 =
      (const _Float16*)Ap + (size_t)(mBase + w * 32 + (lane >> 2)) * K + (lane & 3) * 8;
  const float* gA32 =
      (const float*)Ap + (size_t)(mBase + w * 32 + (lane >> 3)) * K + (lane & 7) * 4;
  const float* gW =
      (const float*)Wp + (size_t)(nBase + w * 32 + (lane >> 3)) * K + (lane & 7) * 4;

  for (int kt = 0; kt < K; kt += 32) {
    if (kt) __syncthreads();
    if constexpr (A16) {
      gload_lds16(gA16 + kt, lA);
      gload_lds16(gA16 + kt + (size_t)16 * K, lA + 512);
    } else {
#pragma unroll
      for (int it = 0; it < 4; ++it) {
        f32x4 v = *(const f32x4*)(gA32 + kt + (size_t)(it * 8) * K);
        h4 o;
        o[0] = (_Float16)v[0]; o[1] = (_Float16)v[1];
        o[2] = (_Float16)v[2]; o[3] = (_Float16)v[3];
        *(h4*)&lA[(it * 8 + (lane >> 3)) * 32 + (lane & 7) * 4] = o;
      }
    }
#pragma unroll
    for (int it = 0; it < 4; ++it) {
      f32x4 v = *(const f32x4*)(gW + kt + (size_t)(it * 8) * K);
      h4 o;
      o[0] = (_Float16)v[0]; o[1] = (_Float16)v[1];
      o[2] = (_Float16)v[2]; o[3] = (_Float16)v[3];
      *(h4*)&lB[(it * 8 + (lane >> 3)) * 32 + (lane & 7) * 4] = o;
    }
    __syncthreads();
    h8 af[4], bf[4];
#pragma unroll
    for (int t = 0; t < 4; ++t) af[t] = *(const h8*)&As[(wr * 64 + t * 16 + li) * 32 + g * 8];
#pragma unroll
    for (int u = 0; u < 4; ++u) bf[u] = *(const h8*)&Bs[(wc * 64 + u * 16 + li) * 32 + g * 8];
#pragma unroll
    for (int t = 0; t < 4; ++t)
#pragma unroll
      for (int u = 0; u < 4; ++u) acc[t][u] = MFMA16(af[t], bf[u], acc[t][u]);
  }

#pragma unroll
  for (int t = 0; t < 4; ++t) {
    const int grow0 = mBase + wr * 64 + t * 16 + g * 4;
#pragma unroll
    for (int u = 0; u < 4; ++u) {
      const int gcol = nBase + wc * 64 + u * 16 + li;
      if (MODE == 2) {
        float* o = (float*)outp;
#pragma unroll
        for (int r = 0; r < 4; ++r) o[(size_t)(grow0 + r) * N + gcol] = acc[t][u][r];
      } else if (MODE == 0) {
        _Float16* o = (_Float16*)outp;
        const int hh = gcol >> 6, d = gcol & 63;
#pragma unroll
        for (int r = 0; r < 4; ++r) {
          const int grow = grow0 + r;
          const int bb = grow >> 11, ss = grow & 2047;
          o[((size_t)((bb * H_ + hh) * S_ + ss)) * 64 + d] = (_Float16)acc[t][u][r];
        }
      } else {  // MODE 1
        _Float16* o = (_Float16*)outp;
        const int hh = gcol >> 6, d = gcol & 63;
        const int bb = grow0 >> 11, ss = grow0 & 2047;
        h4 vv;
#pragma unroll
        for (int r = 0; r < 4; ++r) vv[r] = (_Float16)acc[t][u][r];
        *(h4*)&o[((size_t)((bb * H_ + hh) * 64 + d)) * S_ + ss] = vv;
      }
    }
  }
}

// ---------------- qk1: denominators only, K LDS-staged ----------------
__global__ __launch_bounds__(256, 6)
void qk1_kernel(const _Float16* __restrict__ qh, const _Float16* __restrict__ kh,
                const int* __restrict__ mask, float* __restrict__ rlws) {
  __shared__ _Float16 sbias[S_];
  __shared__ __align__(16) _Float16 Ks[128 * 72];
  const int tid = threadIdx.x;
  const int w = tid >> 6, lane = tid & 63;
  const int g = lane >> 4, li = lane & 15;
  const int id = blockIdx.x;
  const int hh = id & 15, bb = (id >> 4) & 3, qt = id >> 6;
  const size_t bhS = ((size_t)bb * H_ + hh) * S_;
  const _Float16* khb = kh + bhS * 64;

  {
    const int4* mi = (const int4*)(mask + (size_t)bb * S_);
    int4 m0 = mi[tid * 2];
    int4 m1 = mi[tid * 2 + 1];
    _Float16* d = sbias + tid * 8;
    d[0] = m0.x ? (_Float16)BIAS2_MASKED : (_Float16)BIAS2_UNMASKED;
    d[1] = m0.y ? (_Float16)BIAS2_MASKED : (_Float16)BIAS2_UNMASKED;
    d[2] = m0.z ? (_Float16)BIAS2_MASKED : (_Float16)BIAS2_UNMASKED;
    d[3] = m0.w ? (_Float16)BIAS2_MASKED : (_Float16)BIAS2_UNMASKED;
    d[4] = m1.x ? (_Float16)BIAS2_MASKED : (_Float16)BIAS2_UNMASKED;
    d[5] = m1.y ? (_Float16)BIAS2_MASKED : (_Float16)BIAS2_UNMASKED;
    d[6] = m1.z ? (_Float16)BIAS2_MASKED : (_Float16)BIAS2_UNMASKED;
    d[7] = m1.w ? (_Float16)BIAS2_MASKED : (_Float16)BIAS2_UNMASKED;
  }

  h8 aq[2][2];
#pragma unroll
  for (int t = 0; t < 2; ++t) {
    const _Float16* qp = qh + (bhS + qt * 128 + w * 32 + t * 16 + li) * 64;
    aq[t][0] = *(const h8*)(qp + g * 8);
    aq[t][1] = *(const h8*)(qp + 32 + g * 8);
  }

  const int srow = tid >> 3;
  const int ssl = tid & 7;

  float l[2][4] = {};
  for (int kc = 0; kc < 16; ++kc) {
    __syncthreads();
#pragma unroll
    for (int rnd = 0; rnd < 4; ++rnd) {
      const int row = rnd * 32 + srow;
      const h8 kv = *(const h8*)(khb + (size_t)(kc * 128 + row) * 64 + ssl * 8);
      *(h8*)&Ks[row * 72 + ssl * 8] = kv;
    }
    __syncthreads();
    for (int kk = 0; kk < 8; ++kk) {
      const int krow = kk * 16 + li;
      const h8 bk0 = *(const h8*)&Ks[krow * 72 + g * 8];
      const h8 bk1 = *(const h8*)&Ks[krow * 72 + 32 + g * 8];
      const float bias = (float)sbias[kc * 128 + krow];
#pragma unroll
      for (int t = 0; t < 2; ++t) {
        f32x4 a = {0.f, 0.f, 0.f, 0.f};
        a = MFMA16(aq[t][0], bk0, a);
        a = MFMA16(aq[t][1], bk1, a);
#pragma unroll
        for (int r = 0; r < 4; ++r) l[t][r] += exp2f(fmaf(a[r], C_EXP2, bias));
      }
    }
  }

#pragma unroll
  for (int t = 0; t < 2; ++t)
#pragma unroll
    for (int r = 0; r < 4; ++r) {
      float s = l[t][r];
      s += __shfl_xor(s, 1);
      s += __shfl_xor(s, 2);
      s += __shfl_xor(s, 4);
      s += __shfl_xor(s, 8);
      if (li == 0)
        rlws[bhS + qt * 128 + w * 32 + t * 16 + g * 4 + r] = 1.0f / s;
    }
}

// ---------------- qk2: recompute + attn stores + PV; 64-key chunks, 32 KB LDS ----------------
__global__ __launch_bounds__(256, 4)
void qk2_kernel(const _Float16* __restrict__ qh, const _Float16* __restrict__ kh,
                const _Float16* __restrict__ vt, const int* __restrict__ mask,
                const float* __restrict__ rlws, float* __restrict__ attn_out,
                _Float16* __restrict__ ctx) {
  __shared__ _Float16 sbias[S_];                      // 4 KB
  __shared__ __align__(16) _Float16 Ks[64 * 72];      // 9.2 KB
  __shared__ __align__(16) _Float16 Vs[64 * 72];      // 9.2 KB
  __shared__ __align__(16) _Float16 Pst[4][16 * 72];  // 9.2 KB per-wave strips
  const int tid = threadIdx.x;
  const int w = tid >> 6, lane = tid & 63;
  const int g = lane >> 4, li = lane & 15;
  const int id = blockIdx.x;
  const int hh = id & 15, bb = (id >> 4) & 3, qt = id >> 6;
  const size_t bhS = ((size_t)bb * H_ + hh) * S_;
  const _Float16* khb = kh + bhS * 64;
  const _Float16* Vbg = vt + bhS * 64;  // [64][S]

  {
    const int4* mi = (const int4*)(mask + (size_t)bb * S_);
    int4 m0 = mi[tid * 2];
    int4 m1 = mi[tid * 2 + 1];
    _Float16* d = sbias + tid * 8;
    d[0] = m0.x ? (_Float16)BIAS2_MASKED : (_Float16)BIAS2_UNMASKED;
    d[1] = m0.y ? (_Float16)BIAS2_MASKED : (_Float16)BIAS2_UNMASKED;
    d[2] = m0.z ? (_Float16)BIAS2_MASKED : (_Float16)BIAS2_UNMASKED;
    d[3] = m0.w ? (_Float16)BIAS2_MASKED : (_Float16)BIAS2_UNMASKED;
    d[4] = m1.x ? (_Float16)BIAS2_MASKED : (_Float16)BIAS2_UNMASKED;
    d[5] = m1.y ? (_Float16)BIAS2_MASKED : (_Float16)BIAS2_UNMASKED;
    d[6] = m1.z ? (_Float16)BIAS2_MASKED : (_Float16)BIAS2_UNMASKED;
    d[7] = m1.w ? (_Float16)BIAS2_MASKED : (_Float16)BIAS2_UNMASKED;
  }

  h8 aq[2][2];
  float rl[2][4];
#pragma unroll
  for (int t = 0; t < 2; ++t) {
    const _Float16* qp = qh + (bhS + qt * 128 + w * 32 + t * 16 + li) * 64;
    aq[t][0] = *(const h8*)(qp + g * 8);
    aq[t][1] = *(const h8*)(qp + 32 + g * 8);
#pragma unroll
    for (int r = 0; r < 4; ++r)
      rl[t][r] = rlws[bhS + qt * 128 + w * 32 + t * 16 + g * 4 + r];
  }

  float* ab = attn_out + (bhS + qt * 128) * S_;
  _Float16* Pw = &Pst[w][0];
  f32x4 acc[2][4] = {};

  const int srow = tid >> 3;   // staging row-within-32 (2 rounds)
  const int ssl = tid & 7;     // staging 16B slot (8 per 64-key row)
  const int strow = lane >> 4;       // store row-within-4
  const int stcol = (lane & 15) * 4; // store col (x4 floats)

  for (int kc = 0; kc < 32; ++kc) {   // 64-key chunks
    __syncthreads();
#pragma unroll
    for (int rnd = 0; rnd < 2; ++rnd) {
      const int row = rnd * 32 + srow;
      const h8 kv = *(const h8*)(khb + (size_t)(kc * 64 + row) * 64 + ssl * 8);
      *(h8*)&Ks[row * 72 + ssl * 8] = kv;
      const h8 vv = *(const h8*)(Vbg + (size_t)row * S_ + kc * 64 + ssl * 8);
      *(h8*)&Vs[row * 72 + ssl * 8] = vv;
    }
    __syncthreads();

#pragma unroll
    for (int t = 0; t < 2; ++t) {
      // scores -> strip
#pragma unroll
      for (int kk = 0; kk < 4; ++kk) {
        const int krow = kk * 16 + li;
        const h8 bk0 = *(const h8*)&Ks[krow * 72 + g * 8];
        const h8 bk1 = *(const h8*)&Ks[krow * 72 + 32 + g * 8];
        const float bias = (float)sbias[kc * 64 + krow];
        f32x4 a = {0.f, 0.f, 0.f, 0.f};
        a = MFMA16(aq[t][0], bk0, a);
        a = MFMA16(aq[t][1], bk1, a);
#pragma unroll
        for (int r = 0; r < 4; ++r)
          Pw[(g * 4 + r) * 72 + krow] =
              (_Float16)(exp2f(fmaf(a[r], C_EXP2, bias)) * rl[t][r]);
      }
      // attn nt-stores: 4 insts, each 1 KB (4 rows x 256B contiguous)
#pragma unroll
      for (int rr = 0; rr < 4; ++rr) {
        const int row4 = rr * 4 + strow;
        const h4 p = *(const h4*)&Pw[row4 * 72 + stcol];
        f32x4 o;
        o[0] = (float)p[0]; o[1] = (float)p[1];
        o[2] = (float)p[2]; o[3] = (float)p[3];
        __builtin_nontemporal_store(
            o, (f32x4*)(ab + (size_t)(w * 32 + t * 16 + row4) * S_ + kc * 64 + stcol));
      }
      // PV from strip x staged V
#pragma unroll
      for (int ks = 0; ks < 2; ++ks) {
        const h8 pa = *(const h8*)&Pw[li * 72 + ks * 32 + g * 8];
#pragma unroll
        for (int u = 0; u < 4; ++u) {
          const h8 bf = *(const h8*)&Vs[(u * 16 + li) * 72 + ks * 32 + g * 8];
          acc[t][u] = MFMA16(pa, bf, acc[t][u]);
        }
      }
    }
  }

  // epilogue: ctx [B,S,1024] fp16
  _Float16* cb = ctx + ((size_t)bb * S_ + qt * 128 + w * 32 + g * 4) * DM_ + hh * 64 + li;
#pragma unroll
  for (int t = 0; t < 2; ++t)
#pragma unroll
    for (int u = 0; u < 4; ++u)
#pragma unroll
      for (int r = 0; r < 4; ++r)
        cb[(size_t)(t * 16 + r) * DM_ + u * 16] = (_Float16)acc[t][u][r];
}

// ---------------- residual + LayerNorm ----------------
__global__ __launch_bounds__(256)
void ln_kernel(const float* __restrict__ fc, const float* __restrict__ resid,
               const float* __restrict__ gamma, const float* __restrict__ beta,
               float* __restrict__ out) {
  __shared__ float red[8];
  const int row = blockIdx.x;
  const int t = threadIdx.x, w = t >> 6, lane = t & 63;
  const f32x4 xv = *(const f32x4*)(fc + (size_t)row * DM_ + t * 4);
  const f32x4 rv = *(const f32x4*)(resid + (size_t)row * DM_ + t * 4);
  float x0 = xv[0] + rv[0], x1 = xv[1] + rv[1], x2 = xv[2] + rv[2], x3 = xv[3] + rv[3];
  float s = x0 + x1 + x2 + x3;
#pragma unroll
  for (int off = 1; off < 64; off <<= 1) s += __shfl_xor(s, off);
  if (lane == 0) red[w] = s;
  __syncthreads();
  const float mu = (red[0] + red[1] + red[2] + red[3]) * (1.0f / (float)DM_);
  const float d0 = x0 - mu, d1 = x1 - mu, d2 = x2 - mu, d3 = x3 - mu;
  float sq = d0 * d0 + d1 * d1 + d2 * d2 + d3 * d3;
#pragma unroll
  for (int off = 1; off < 64; off <<= 1) sq += __shfl_xor(sq, off);
  if (lane == 0) red[4 + w] = sq;
  __syncthreads();
  const float inv = rsqrtf((red[4] + red[5] + red[6] + red[7]) * (1.0f / (float)DM_) + 1e-5f);
  const f32x4 gv = *(const f32x4*)(gamma + t * 4);
  const f32x4 bv = *(const f32x4*)(beta + t * 4);
  f32x4 o;
  o[0] = d0 * inv * gv[0] + bv[0];
  o[1] = d1 * inv * gv[1] + bv[1];
  o[2] = d2 * inv * gv[2] + bv[2];
  o[3] = d3 * inv * gv[3] + bv[3];
  *(f32x4*)(out + (size_t)row * DM_ + t * 4) = o;
}

// ---------------- launch ----------------
extern "C" void kernel_launch(void* const* d_in, const int* in_sizes, int n_in,
                              void* d_out, int out_size, void* d_ws, size_t ws_size,
                              hipStream_t stream) {
  const float* q = (const float*)d_in[0];
  const float* k = (const float*)d_in[1];
  const float* v = (const float*)d_in[2];
  const int* mask = (const int*)d_in[3];
  const float* wq = (const float*)d_in[4];
  const float* wk = (const float*)d_in[5];
  const float* wv = (const float*)d_in[6];
  const float* wfc = (const float*)d_in[7];
  const float* gamma = (const float*)d_in[8];
  const float* beta = (const float*)d_in[9];

  float* out0 = (float*)d_out;                  // [B,S,DM]
  float* attn = out0 + (size_t)B_ * S_ * DM_;   // [B,H,S,S] fp32
  float* rlws = out0;  // 512 KB scratch inside d_out; ln overwrites it at the end

  // workspace layout — 64 MB total.
  //   0-16 qhp | 16-32 khp | 32-48 vtp | 48-64 ctxp
  //   stg (fp16 staging for cvt, 16 MB) = ctxp slot, reused serially:
  //     cvt q->stg, gemm q; cvt k->stg, gemm k; cvt v->stg, gemm v; then qk2
  //     writes ctxp (stg dead). fcp (32 MB) overlays qhp+khp after qk2.
  char* ws = (char*)d_ws;
  _Float16* qhp = (_Float16*)(ws + (0ull << 20));
  _Float16* khp = (_Float16*)(ws + (16ull << 20));
  _Float16* vtp = (_Float16*)(ws + (32ull << 20));
  _Float16* ctxp = (_Float16*)(ws + (48ull << 20));
  float* fcp = (float*)(ws + (0ull << 20));
  _Float16* stg = (_Float16*)(ws + (48ull << 20));  // 16 MB staging (ctxp slot)

  const int nqkv4 = B_ * S_ * DM_ / 4;  // 2097152
  dim3 gg(DM_ / 128, B_ * S_ / 128);    // (8, 64)

  cvt_kernel<<<nqkv4 / 256, 256, 0, stream>>>(q, stg, nqkv4);
  gemm_bt<0, 1><<<gg, 256, 0, stream>>>(stg, wq, qhp, B_ * S_, DM_, DM_);
  cvt_kernel<<<nqkv4 / 256, 256, 0, stream>>>(k, stg, nqkv4);
  gemm_bt<0, 1><<<gg, 256, 0, stream>>>(stg, wk, khp, B_ * S_, DM_, DM_);
  cvt_kernel<<<nqkv4 / 256, 256, 0, stream>>>(v, stg, nqkv4);
  gemm_bt<1, 1><<<gg, 256, 0, stream>>>(stg, wv, vtp, B_ * S_, DM_, DM_);

  qk1_kernel<<<dim3(1024), 256, 0, stream>>>(qhp, khp, mask, rlws);
  qk2_kernel<<<dim3(1024), 256, 0, stream>>>(qhp, khp, vtp, mask, rlws, attn, ctxp);

  gemm_bt<2, 1><<<gg, 256, 0, stream>>>(ctxp, wfc, fcp, B_ * S_, DM_, DM_);

  ln_kernel<<<B_ * S_, 256, 0, stream>>>(fcp, q, gamma, beta, out0);
}

// Round 18
// 503.633 us; speedup vs baseline: 1.1446x; 1.1446x over previous
//
#include <hip/hip_runtime.h>
#include <cstdint>
#include <cstddef>
#include <cmath>

// ---- problem constants ----
#define B_  4
#define S_  2048
#define DM_ 1024
#define H_  16

typedef _Float16 h8 __attribute__((ext_vector_type(8)));
typedef _Float16 h4 __attribute__((ext_vector_type(4)));
typedef float f32x4 __attribute__((ext_vector_type(4)));

#define MFMA16(A_, B2_, C_) __builtin_amdgcn_mfma_f32_16x16x32_f16((A_), (B2_), (C_), 0, 0, 0)

// exp2 folding: p = exp2(a * (0.125*log2e) + bias2); fp16 rounding of bias2 cancels
// exactly between the denominator pass and the numerator pass (identical expressions).
#define C_EXP2 0.18033688011112042f
#define BIAS2_UNMASKED -14.426950408889634f
#define BIAS2_MASKED   -60000.0f

__device__ __forceinline__ void gload_lds16(const void* g, void* l) {
  __builtin_amdgcn_global_load_lds(
      (const __attribute__((address_space(1))) unsigned int*)g,
      (__attribute__((address_space(3))) unsigned int*)l, 16, 0, 0);
}

// ---------------- GEMM: C[m,n] = sum_k A[m,k] * W[n,k] ----------------
// A16: A operand fp16 (global_load_lds); else fp32 (reg-convert staging).
// MODE 0: out fp16 scatter qh/kh [B,H,S,64]; MODE 1: out fp16 vt [B,H,64,S];
// MODE 2: out fp32 row-major [M,N]
template <int MODE, int A16>
__global__ __launch_bounds__(256, 2)
void gemm_bt(const void* __restrict__ Ap, const void* __restrict__ Wp,
             void* __restrict__ outp, int M, int N, int K) {
  __shared__ _Float16 As[128 * 32];
  __shared__ _Float16 Bs[128 * 32];
  const int tid = threadIdx.x;
  const int w = tid >> 6, lane = tid & 63;
  const int g = lane >> 4, li = lane & 15;
  const int wr = w >> 1, wc = w & 1;
  const int mBase = blockIdx.y * 128, nBase = blockIdx.x * 128;

  f32x4 acc[4][4] = {};

  _Float16* lA = As + w * 1024;
  _Float16* lB = Bs + w * 1024;

  const _Float16* gA16 =
      (const _Float16*)Ap + (size_t)(mBase + w * 32 + (lane >> 2)) * K + (lane & 3) * 8;
  const float* gA32 =
      (const float*)Ap + (size_t)(mBase + w * 32 + (lane >> 3)) * K + (lane & 7) * 4;
  const float* gW =
      (const float*)Wp + (size_t)(nBase + w * 32 + (lane >> 3)) * K + (lane & 7) * 4;

  for (int kt = 0; kt < K; kt += 32) {
    if (kt) __syncthreads();
    if constexpr (A16) {
      gload_lds16(gA16 + kt, lA);
      gload_lds16(gA16 + kt + (size_t)16 * K, lA + 512);
    } else {
#pragma unroll
      for (int it = 0; it < 4; ++it) {
        f32x4 v = *(const f32x4*)(gA32 + kt + (size_t)(it * 8) * K);
        h4 o;
        o[0] = (_Float16)v[0]; o[1] = (_Float16)v[1];
        o[2] = (_Float16)v[2]; o[3] = (_Float16)v[3];
        *(h4*)&lA[(it * 8 + (lane >> 3)) * 32 + (lane & 7) * 4] = o;
      }
    }
#pragma unroll
    for (int it = 0; it < 4; ++it) {
      f32x4 v = *(const f32x4*)(gW + kt + (size_t)(it * 8) * K);
      h4 o;
      o[0] = (_Float16)v[0]; o[1] = (_Float16)v[1];
      o[2] = (_Float16)v[2]; o[3] = (_Float16)v[3];
      *(h4*)&lB[(it * 8 + (lane >> 3)) * 32 + (lane & 7) * 4] = o;
    }
    __syncthreads();
    h8 af[4], bf[4];
#pragma unroll
    for (int t = 0; t < 4; ++t) af[t] = *(const h8*)&As[(wr * 64 + t * 16 + li) * 32 + g * 8];
#pragma unroll
    for (int u = 0; u < 4; ++u) bf[u] = *(const h8*)&Bs[(wc * 64 + u * 16 + li) * 32 + g * 8];
#pragma unroll
    for (int t = 0; t < 4; ++t)
#pragma unroll
      for (int u = 0; u < 4; ++u) acc[t][u] = MFMA16(af[t], bf[u], acc[t][u]);
  }

#pragma unroll
  for (int t = 0; t < 4; ++t) {
    const int grow0 = mBase + wr * 64 + t * 16 + g * 4;
#pragma unroll
    for (int u = 0; u < 4; ++u) {
      const int gcol = nBase + wc * 64 + u * 16 + li;
      if (MODE == 2) {
        float* o = (float*)outp;
#pragma unroll
        for (int r = 0; r < 4; ++r) o[(size_t)(grow0 + r) * N + gcol] = acc[t][u][r];
      } else if (MODE == 0) {
        _Float16* o = (_Float16*)outp;
        const int hh = gcol >> 6, d = gcol & 63;
#pragma unroll
        for (int r = 0; r < 4; ++r) {
          const int grow = grow0 + r;
          const int bb = grow >> 11, ss = grow & 2047;
          o[((size_t)((bb * H_ + hh) * S_ + ss)) * 64 + d] = (_Float16)acc[t][u][r];
        }
      } else {  // MODE 1
        _Float16* o = (_Float16*)outp;
        const int hh = gcol >> 6, d = gcol & 63;
        const int bb = grow0 >> 11, ss = grow0 & 2047;
        h4 vv;
#pragma unroll
        for (int r = 0; r < 4; ++r) vv[r] = (_Float16)acc[t][u][r];
        *(h4*)&o[((size_t)((bb * H_ + hh) * 64 + d)) * S_ + ss] = vv;
      }
    }
  }
}

// ---------------- fused attention: phase1 (denominators) + phase2 (stores+PV) ----------
// 1024 blocks: id = (qt*4+bb)*16 + hh (h-affine to XCD). Block = 128 q-rows of (bb,hh).
// 4 waves; wave w owns rows w*32..+32 (two 16-row tiles). 64-key LDS chunks, 32 KB.
__global__ __launch_bounds__(256, 4)
void attn_kernel(const _Float16* __restrict__ qh, const _Float16* __restrict__ kh,
                 const _Float16* __restrict__ vt, const int* __restrict__ mask,
                 float* __restrict__ attn_out, _Float16* __restrict__ ctx) {
  __shared__ _Float16 sbias[S_];                      // 4 KB
  __shared__ __align__(16) _Float16 Ks[64 * 72];      // 9.2 KB
  __shared__ __align__(16) _Float16 Vs[64 * 72];      // 9.2 KB
  __shared__ __align__(16) _Float16 Pst[4][16 * 72];  // 9.2 KB per-wave strips
  const int tid = threadIdx.x;
  const int w = tid >> 6, lane = tid & 63;
  const int g = lane >> 4, li = lane & 15;
  const int id = blockIdx.x;
  const int hh = id & 15, bb = (id >> 4) & 3, qt = id >> 6;
  const size_t bhS = ((size_t)bb * H_ + hh) * S_;
  const _Float16* khb = kh + bhS * 64;
  const _Float16* Vbg = vt + bhS * 64;  // [64][S]

  {
    const int4* mi = (const int4*)(mask + (size_t)bb * S_);
    int4 m0 = mi[tid * 2];
    int4 m1 = mi[tid * 2 + 1];
    _Float16* d = sbias + tid * 8;
    d[0] = m0.x ? (_Float16)BIAS2_MASKED : (_Float16)BIAS2_UNMASKED;
    d[1] = m0.y ? (_Float16)BIAS2_MASKED : (_Float16)BIAS2_UNMASKED;
    d[2] = m0.z ? (_Float16)BIAS2_MASKED : (_Float16)BIAS2_UNMASKED;
    d[3] = m0.w ? (_Float16)BIAS2_MASKED : (_Float16)BIAS2_UNMASKED;
    d[4] = m1.x ? (_Float16)BIAS2_MASKED : (_Float16)BIAS2_UNMASKED;
    d[5] = m1.y ? (_Float16)BIAS2_MASKED : (_Float16)BIAS2_UNMASKED;
    d[6] = m1.z ? (_Float16)BIAS2_MASKED : (_Float16)BIAS2_UNMASKED;
    d[7] = m1.w ? (_Float16)BIAS2_MASKED : (_Float16)BIAS2_UNMASKED;
  }

  // Q fragments in registers (loop-invariant, shared by both phases)
  h8 aq[2][2];
#pragma unroll
  for (int t = 0; t < 2; ++t) {
    const _Float16* qp = qh + (bhS + qt * 128 + w * 32 + t * 16 + li) * 64;
    aq[t][0] = *(const h8*)(qp + g * 8);
    aq[t][1] = *(const h8*)(qp + 32 + g * 8);
  }

  const int srow = tid >> 3;   // staging row-within-32
  const int ssl = tid & 7;     // staging 16B slot (8 per 64-half row)

  // ---- phase 1: denominators (K staged per 64-key chunk; includes sbias sync) ----
  float l[2][4] = {};
  for (int kc = 0; kc < 32; ++kc) {
    __syncthreads();  // covers sbias staging at kc=0; prior Ks reads after
#pragma unroll
    for (int rnd = 0; rnd < 2; ++rnd) {
      const int row = rnd * 32 + srow;
      const h8 kv = *(const h8*)(khb + (size_t)(kc * 64 + row) * 64 + ssl * 8);
      *(h8*)&Ks[row * 72 + ssl * 8] = kv;
    }
    __syncthreads();
#pragma unroll
    for (int kk = 0; kk < 4; ++kk) {
      const int krow = kk * 16 + li;
      const h8 bk0 = *(const h8*)&Ks[krow * 72 + g * 8];
      const h8 bk1 = *(const h8*)&Ks[krow * 72 + 32 + g * 8];
      const float bias = (float)sbias[kc * 64 + krow];
#pragma unroll
      for (int t = 0; t < 2; ++t) {
        f32x4 a = {0.f, 0.f, 0.f, 0.f};
        a = MFMA16(aq[t][0], bk0, a);
        a = MFMA16(aq[t][1], bk1, a);
#pragma unroll
        for (int r = 0; r < 4; ++r) l[t][r] += exp2f(fmaf(a[r], C_EXP2, bias));
      }
    }
  }

  float rl[2][4];
#pragma unroll
  for (int t = 0; t < 2; ++t)
#pragma unroll
    for (int r = 0; r < 4; ++r) {
      float s = l[t][r];
      s += __shfl_xor(s, 1);
      s += __shfl_xor(s, 2);
      s += __shfl_xor(s, 4);
      s += __shfl_xor(s, 8);
      rl[t][r] = 1.0f / s;  // kept in registers — no global round-trip
    }

  // ---- phase 2: recompute, strip, 1 KB nt-stores, PV ----
  float* ab = attn_out + (bhS + qt * 128) * S_;
  _Float16* Pw = &Pst[w][0];
  f32x4 acc[2][4] = {};
  const int strow = lane >> 4;        // store row-within-4
  const int stcol = (lane & 15) * 4;  // store col (x4 floats)

  for (int kc = 0; kc < 32; ++kc) {
    __syncthreads();  // all waves past phase-1 / prior-chunk Ks/Vs reads
#pragma unroll
    for (int rnd = 0; rnd < 2; ++rnd) {
      const int row = rnd * 32 + srow;
      const h8 kv = *(const h8*)(khb + (size_t)(kc * 64 + row) * 64 + ssl * 8);
      *(h8*)&Ks[row * 72 + ssl * 8] = kv;
      const h8 vv = *(const h8*)(Vbg + (size_t)row * S_ + kc * 64 + ssl * 8);
      *(h8*)&Vs[row * 72 + ssl * 8] = vv;
    }
    __syncthreads();

#pragma unroll
    for (int t = 0; t < 2; ++t) {
      // scores -> strip
#pragma unroll
      for (int kk = 0; kk < 4; ++kk) {
        const int krow = kk * 16 + li;
        const h8 bk0 = *(const h8*)&Ks[krow * 72 + g * 8];
        const h8 bk1 = *(const h8*)&Ks[krow * 72 + 32 + g * 8];
        const float bias = (float)sbias[kc * 64 + krow];
        f32x4 a = {0.f, 0.f, 0.f, 0.f};
        a = MFMA16(aq[t][0], bk0, a);
        a = MFMA16(aq[t][1], bk1, a);
#pragma unroll
        for (int r = 0; r < 4; ++r)
          Pw[(g * 4 + r) * 72 + krow] =
              (_Float16)(exp2f(fmaf(a[r], C_EXP2, bias)) * rl[t][r]);
      }
      // attn nt-stores: 4 insts, each 1 KB (4 rows x 256B contiguous)
#pragma unroll
      for (int rr = 0; rr < 4; ++rr) {
        const int row4 = rr * 4 + strow;
        const h4 p = *(const h4*)&Pw[row4 * 72 + stcol];
        f32x4 o;
        o[0] = (float)p[0]; o[1] = (float)p[1];
        o[2] = (float)p[2]; o[3] = (float)p[3];
        __builtin_nontemporal_store(
            o, (f32x4*)(ab + (size_t)(w * 32 + t * 16 + row4) * S_ + kc * 64 + stcol));
      }
      // PV from strip x staged V
#pragma unroll
      for (int ks = 0; ks < 2; ++ks) {
        const h8 pa = *(const h8*)&Pw[li * 72 + ks * 32 + g * 8];
#pragma unroll
        for (int u = 0; u < 4; ++u) {
          const h8 bf = *(const h8*)&Vs[(u * 16 + li) * 72 + ks * 32 + g * 8];
          acc[t][u] = MFMA16(pa, bf, acc[t][u]);
        }
      }
    }
  }

  // epilogue: ctx [B,S,1024] fp16
  _Float16* cb = ctx + ((size_t)bb * S_ + qt * 128 + w * 32 + g * 4) * DM_ + hh * 64 + li;
#pragma unroll
  for (int t = 0; t < 2; ++t)
#pragma unroll
    for (int u = 0; u < 4; ++u)
#pragma unroll
      for (int r = 0; r < 4; ++r)
        cb[(size_t)(t * 16 + r) * DM_ + u * 16] = (_Float16)acc[t][u][r];
}

// ---------------- residual + LayerNorm ----------------
__global__ __launch_bounds__(256)
void ln_kernel(const float* __restrict__ fc, const float* __restrict__ resid,
               const float* __restrict__ gamma, const float* __restrict__ beta,
               float* __restrict__ out) {
  __shared__ float red[8];
  const int row = blockIdx.x;
  const int t = threadIdx.x, w = t >> 6, lane = t & 63;
  const f32x4 xv = *(const f32x4*)(fc + (size_t)row * DM_ + t * 4);
  const f32x4 rv = *(const f32x4*)(resid + (size_t)row * DM_ + t * 4);
  float x0 = xv[0] + rv[0], x1 = xv[1] + rv[1], x2 = xv[2] + rv[2], x3 = xv[3] + rv[3];
  float s = x0 + x1 + x2 + x3;
#pragma unroll
  for (int off = 1; off < 64; off <<= 1) s += __shfl_xor(s, off);
  if (lane == 0) red[w] = s;
  __syncthreads();
  const float mu = (red[0] + red[1] + red[2] + red[3]) * (1.0f / (float)DM_);
  const float d0 = x0 - mu, d1 = x1 - mu, d2 = x2 - mu, d3 = x3 - mu;
  float sq = d0 * d0 + d1 * d1 + d2 * d2 + d3 * d3;
#pragma unroll
  for (int off = 1; off < 64; off <<= 1) sq += __shfl_xor(sq, off);
  if (lane == 0) red[4 + w] = sq;
  __syncthreads();
  const float inv = rsqrtf((red[4] + red[5] + red[6] + red[7]) * (1.0f / (float)DM_) + 1e-5f);
  const f32x4 gv = *(const f32x4*)(gamma + t * 4);
  const f32x4 bv = *(const f32x4*)(beta + t * 4);
  f32x4 o;
  o[0] = d0 * inv * gv[0] + bv[0];
  o[1] = d1 * inv * gv[1] + bv[1];
  o[2] = d2 * inv * gv[2] + bv[2];
  o[3] = d3 * inv * gv[3] + bv[3];
  *(f32x4*)(out + (size_t)row * DM_ + t * 4) = o;
}

// ---------------- launch ----------------
extern "C" void kernel_launch(void* const* d_in, const int* in_sizes, int n_in,
                              void* d_out, int out_size, void* d_ws, size_t ws_size,
                              hipStream_t stream) {
  const float* q = (const float*)d_in[0];
  const float* k = (const float*)d_in[1];
  const float* v = (const float*)d_in[2];
  const int* mask = (const int*)d_in[3];
  const float* wq = (const float*)d_in[4];
  const float* wk = (const float*)d_in[5];
  const float* wv = (const float*)d_in[6];
  const float* wfc = (const float*)d_in[7];
  const float* gamma = (const float*)d_in[8];
  const float* beta = (const float*)d_in[9];

  float* out0 = (float*)d_out;                  // [B,S,DM]
  float* attn = out0 + (size_t)B_ * S_ * DM_;   // [B,H,S,S] fp32

  // workspace layout — 64 MB total (fcp overlays qhp+khp, dead after attn)
  char* ws = (char*)d_ws;
  _Float16* qhp = (_Float16*)(ws + (0ull << 20));   // [B,H,S,64]   16 MB
  _Float16* khp = (_Float16*)(ws + (16ull << 20));  // [B,H,S,64]   16 MB
  _Float16* vtp = (_Float16*)(ws + (32ull << 20));  // [B,H,64,S]   16 MB
  _Float16* ctxp = (_Float16*)(ws + (48ull << 20)); // [B,S,1024]   16 MB
  float* fcp = (float*)(ws + (0ull << 20));         // [B*S,1024] fp32, 32 MB (overlay)

  dim3 gg(DM_ / 128, B_ * S_ / 128);  // (8, 64)
  gemm_bt<0, 0><<<gg, 256, 0, stream>>>(q, wq, qhp, B_ * S_, DM_, DM_);
  gemm_bt<0, 0><<<gg, 256, 0, stream>>>(k, wk, khp, B_ * S_, DM_, DM_);
  gemm_bt<1, 0><<<gg, 256, 0, stream>>>(v, wv, vtp, B_ * S_, DM_, DM_);

  attn_kernel<<<dim3(1024), 256, 0, stream>>>(qhp, khp, vtp, mask, attn, ctxp);

  gemm_bt<2, 1><<<gg, 256, 0, stream>>>(ctxp, wfc, fcp, B_ * S_, DM_, DM_);

  ln_kernel<<<B_ * S_, 256, 0, stream>>>(fcp, q, gamma, beta, out0);
}

// Round 19
// 491.338 us; speedup vs baseline: 1.1732x; 1.0250x over previous
//
#include <hip/hip_runtime.h>
#include <cstdint>
#include <cstddef>
#include <cmath>

// ---- problem constants ----
#define B_  4
#define S_  2048
#define DM_ 1024
#define H_  16

typedef _Float16 h8 __attribute__((ext_vector_type(8)));
typedef _Float16 h4 __attribute__((ext_vector_type(4)));
typedef float f32x4 __attribute__((ext_vector_type(4)));

#define MFMA16(A_, B2_, C_) __builtin_amdgcn_mfma_f32_16x16x32_f16((A_), (B2_), (C_), 0, 0, 0)

// exp2 folding: p = exp2(a * (0.125*log2e) + bias2); fp16 rounding of bias2 cancels
// exactly between the denominator pass and the numerator pass (identical expressions).
#define C_EXP2 0.18033688011112042f
#define BIAS2_UNMASKED -14.426950408889634f
#define BIAS2_MASKED   -60000.0f

__device__ __forceinline__ void gload_lds16(const void* g, void* l) {
  __builtin_amdgcn_global_load_lds(
      (const __attribute__((address_space(1))) unsigned int*)g,
      (__attribute__((address_space(3))) unsigned int*)l, 16, 0, 0);
}

// ---------------- fused 3-way projection GEMM: z selects {q,k,v} ----------------
// C[m,n] = sum_k A[m,k] * W[n,k]; A fp32 (reg-convert staging), W fp32.
// z=0: qh scatter [B,H,S,64]; z=1: kh scatter; z=2: vt [B,H,64,S].
__global__ __launch_bounds__(256, 2)
void gemm3_kernel(const float* __restrict__ q, const float* __restrict__ k,
                  const float* __restrict__ v, const float* __restrict__ wq,
                  const float* __restrict__ wk, const float* __restrict__ wv,
                  _Float16* __restrict__ qhp, _Float16* __restrict__ khp,
                  _Float16* __restrict__ vtp) {
  __shared__ _Float16 As[128 * 32];
  __shared__ _Float16 Bs[128 * 32];
  const int tid = threadIdx.x;
  const int w = tid >> 6, lane = tid & 63;
  const int g = lane >> 4, li = lane & 15;
  const int wr = w >> 1, wc = w & 1;
  const int mBase = blockIdx.y * 128, nBase = blockIdx.x * 128;
  const int z = blockIdx.z;
  const int K = DM_;

  const float* Ap = (z == 0) ? q : (z == 1) ? k : v;
  const float* Wp = (z == 0) ? wq : (z == 1) ? wk : wv;

  f32x4 acc[4][4] = {};

  _Float16* lA = As + w * 1024;
  _Float16* lB = Bs + w * 1024;

  const float* gA32 = Ap + (size_t)(mBase + w * 32 + (lane >> 3)) * K + (lane & 7) * 4;
  const float* gW = Wp + (size_t)(nBase + w * 32 + (lane >> 3)) * K + (lane & 7) * 4;

  for (int kt = 0; kt < K; kt += 32) {
    if (kt) __syncthreads();
#pragma unroll
    for (int it = 0; it < 4; ++it) {
      f32x4 va = *(const f32x4*)(gA32 + kt + (size_t)(it * 8) * K);
      h4 oa;
      oa[0] = (_Float16)va[0]; oa[1] = (_Float16)va[1];
      oa[2] = (_Float16)va[2]; oa[3] = (_Float16)va[3];
      *(h4*)&lA[(it * 8 + (lane >> 3)) * 32 + (lane & 7) * 4] = oa;
      f32x4 vw = *(const f32x4*)(gW + kt + (size_t)(it * 8) * K);
      h4 ow;
      ow[0] = (_Float16)vw[0]; ow[1] = (_Float16)vw[1];
      ow[2] = (_Float16)vw[2]; ow[3] = (_Float16)vw[3];
      *(h4*)&lB[(it * 8 + (lane >> 3)) * 32 + (lane & 7) * 4] = ow;
    }
    __syncthreads();
    h8 af[4], bf[4];
#pragma unroll
    for (int t = 0; t < 4; ++t) af[t] = *(const h8*)&As[(wr * 64 + t * 16 + li) * 32 + g * 8];
#pragma unroll
    for (int u = 0; u < 4; ++u) bf[u] = *(const h8*)&Bs[(wc * 64 + u * 16 + li) * 32 + g * 8];
#pragma unroll
    for (int t = 0; t < 4; ++t)
#pragma unroll
      for (int u = 0; u < 4; ++u) acc[t][u] = MFMA16(af[t], bf[u], acc[t][u]);
  }

#pragma unroll
  for (int t = 0; t < 4; ++t) {
    const int grow0 = mBase + wr * 64 + t * 16 + g * 4;
#pragma unroll
    for (int u = 0; u < 4; ++u) {
      const int gcol = nBase + wc * 64 + u * 16 + li;
      const int hh = gcol >> 6, d = gcol & 63;
      if (z != 2) {
        _Float16* o = (z == 0) ? qhp : khp;
#pragma unroll
        for (int r = 0; r < 4; ++r) {
          const int grow = grow0 + r;
          const int bb = grow >> 11, ss = grow & 2047;
          o[((size_t)((bb * H_ + hh) * S_ + ss)) * 64 + d] = (_Float16)acc[t][u][r];
        }
      } else {  // vt [B,H,64,S]; grow0..+3 share b (4-aligned)
        const int bb = grow0 >> 11, ss = grow0 & 2047;
        h4 vv;
#pragma unroll
        for (int r = 0; r < 4; ++r) vv[r] = (_Float16)acc[t][u][r];
        *(h4*)&vtp[((size_t)((bb * H_ + hh) * 64 + d)) * S_ + ss] = vv;
      }
    }
  }
}

// ---------------- fc GEMM: C[m,n] = sum_k A[m,k]*W[n,k], A fp16, out fp32 ----------------
__global__ __launch_bounds__(256, 2)
void gemm_fc(const _Float16* __restrict__ Ap, const float* __restrict__ Wp,
             float* __restrict__ outp, int M, int N, int K) {
  __shared__ _Float16 As[128 * 32];
  __shared__ _Float16 Bs[128 * 32];
  const int tid = threadIdx.x;
  const int w = tid >> 6, lane = tid & 63;
  const int g = lane >> 4, li = lane & 15;
  const int wr = w >> 1, wc = w & 1;
  const int mBase = blockIdx.y * 128, nBase = blockIdx.x * 128;

  f32x4 acc[4][4] = {};

  _Float16* lA = As + w * 1024;
  _Float16* lB = Bs + w * 1024;

  const _Float16* gA16 =
      Ap + (size_t)(mBase + w * 32 + (lane >> 2)) * K + (lane & 3) * 8;
  const float* gW = Wp + (size_t)(nBase + w * 32 + (lane >> 3)) * K + (lane & 7) * 4;

  for (int kt = 0; kt < K; kt += 32) {
    if (kt) __syncthreads();
    gload_lds16(gA16 + kt, lA);
    gload_lds16(gA16 + kt + (size_t)16 * K, lA + 512);
#pragma unroll
    for (int it = 0; it < 4; ++it) {
      f32x4 vw = *(const f32x4*)(gW + kt + (size_t)(it * 8) * K);
      h4 ow;
      ow[0] = (_Float16)vw[0]; ow[1] = (_Float16)vw[1];
      ow[2] = (_Float16)vw[2]; ow[3] = (_Float16)vw[3];
      *(h4*)&lB[(it * 8 + (lane >> 3)) * 32 + (lane & 7) * 4] = ow;
    }
    __syncthreads();
    h8 af[4], bf[4];
#pragma unroll
    for (int t = 0; t < 4; ++t) af[t] = *(const h8*)&As[(wr * 64 + t * 16 + li) * 32 + g * 8];
#pragma unroll
    for (int u = 0; u < 4; ++u) bf[u] = *(const h8*)&Bs[(wc * 64 + u * 16 + li) * 32 + g * 8];
#pragma unroll
    for (int t = 0; t < 4; ++t)
#pragma unroll
      for (int u = 0; u < 4; ++u) acc[t][u] = MFMA16(af[t], bf[u], acc[t][u]);
  }

#pragma unroll
  for (int t = 0; t < 4; ++t) {
    const int grow0 = mBase + wr * 64 + t * 16 + g * 4;
#pragma unroll
    for (int u = 0; u < 4; ++u) {
      const int gcol = nBase + wc * 64 + u * 16 + li;
#pragma unroll
      for (int r = 0; r < 4; ++r) outp[(size_t)(grow0 + r) * N + gcol] = acc[t][u][r];
    }
  }
}

// ---------------- fused attention: phase1 (denominators) + phase2 (stores+PV) ----------
// 1024 blocks: id = (qt*4+bb)*16 + hh (h-affine to XCD). Block = 128 q-rows of (bb,hh).
// 4 waves; wave w owns rows w*32..+32 (two 16-row tiles). 64-key LDS chunks, 32 KB.
__global__ __launch_bounds__(256, 4)
void attn_kernel(const _Float16* __restrict__ qh, const _Float16* __restrict__ kh,
                 const _Float16* __restrict__ vt, const int* __restrict__ mask,
                 float* __restrict__ attn_out, _Float16* __restrict__ ctx) {
  __shared__ _Float16 sbias[S_];                      // 4 KB
  __shared__ __align__(16) _Float16 Ks[64 * 72];      // 9.2 KB
  __shared__ __align__(16) _Float16 Vs[64 * 72];      // 9.2 KB
  __shared__ __align__(16) _Float16 Pst[4][16 * 72];  // 9.2 KB per-wave strips
  const int tid = threadIdx.x;
  const int w = tid >> 6, lane = tid & 63;
  const int g = lane >> 4, li = lane & 15;
  const int id = blockIdx.x;
  const int hh = id & 15, bb = (id >> 4) & 3, qt = id >> 6;
  const size_t bhS = ((size_t)bb * H_ + hh) * S_;
  const _Float16* khb = kh + bhS * 64;
  const _Float16* Vbg = vt + bhS * 64;  // [64][S]

  {
    const int4* mi = (const int4*)(mask + (size_t)bb * S_);
    int4 m0 = mi[tid * 2];
    int4 m1 = mi[tid * 2 + 1];
    _Float16* d = sbias + tid * 8;
    d[0] = m0.x ? (_Float16)BIAS2_MASKED : (_Float16)BIAS2_UNMASKED;
    d[1] = m0.y ? (_Float16)BIAS2_MASKED : (_Float16)BIAS2_UNMASKED;
    d[2] = m0.z ? (_Float16)BIAS2_MASKED : (_Float16)BIAS2_UNMASKED;
    d[3] = m0.w ? (_Float16)BIAS2_MASKED : (_Float16)BIAS2_UNMASKED;
    d[4] = m1.x ? (_Float16)BIAS2_MASKED : (_Float16)BIAS2_UNMASKED;
    d[5] = m1.y ? (_Float16)BIAS2_MASKED : (_Float16)BIAS2_UNMASKED;
    d[6] = m1.z ? (_Float16)BIAS2_MASKED : (_Float16)BIAS2_UNMASKED;
    d[7] = m1.w ? (_Float16)BIAS2_MASKED : (_Float16)BIAS2_UNMASKED;
  }

  // Q fragments in registers (loop-invariant, shared by both phases)
  h8 aq[2][2];
#pragma unroll
  for (int t = 0; t < 2; ++t) {
    const _Float16* qp = qh + (bhS + qt * 128 + w * 32 + t * 16 + li) * 64;
    aq[t][0] = *(const h8*)(qp + g * 8);
    aq[t][1] = *(const h8*)(qp + 32 + g * 8);
  }

  const int srow = tid >> 3;   // staging row-within-32
  const int ssl = tid & 7;     // staging 16B slot (8 per 64-half row)

  // ---- phase 1: denominators (K staged per 64-key chunk; includes sbias sync) ----
  float l[2][4] = {};
  for (int kc = 0; kc < 32; ++kc) {
    __syncthreads();  // covers sbias staging at kc=0; prior Ks reads after
#pragma unroll
    for (int rnd = 0; rnd < 2; ++rnd) {
      const int row = rnd * 32 + srow;
      const h8 kv = *(const h8*)(khb + (size_t)(kc * 64 + row) * 64 + ssl * 8);
      *(h8*)&Ks[row * 72 + ssl * 8] = kv;
    }
    __syncthreads();
#pragma unroll
    for (int kk = 0; kk < 4; ++kk) {
      const int krow = kk * 16 + li;
      const h8 bk0 = *(const h8*)&Ks[krow * 72 + g * 8];
      const h8 bk1 = *(const h8*)&Ks[krow * 72 + 32 + g * 8];
      const float bias = (float)sbias[kc * 64 + krow];
#pragma unroll
      for (int t = 0; t < 2; ++t) {
        f32x4 a = {0.f, 0.f, 0.f, 0.f};
        a = MFMA16(aq[t][0], bk0, a);
        a = MFMA16(aq[t][1], bk1, a);
#pragma unroll
        for (int r = 0; r < 4; ++r) l[t][r] += exp2f(fmaf(a[r], C_EXP2, bias));
      }
    }
  }

  float rl[2][4];
#pragma unroll
  for (int t = 0; t < 2; ++t)
#pragma unroll
    for (int r = 0; r < 4; ++r) {
      float s = l[t][r];
      s += __shfl_xor(s, 1);
      s += __shfl_xor(s, 2);
      s += __shfl_xor(s, 4);
      s += __shfl_xor(s, 8);
      rl[t][r] = 1.0f / s;  // kept in registers — no global round-trip
    }

  // ---- phase 2: recompute, strip, 1 KB nt-stores, PV ----
  float* ab = attn_out + (bhS + qt * 128) * S_;
  _Float16* Pw = &Pst[w][0];
  f32x4 acc[2][4] = {};
  const int strow = lane >> 4;        // store row-within-4
  const int stcol = (lane & 15) * 4;  // store col (x4 floats)

  for (int kc = 0; kc < 32; ++kc) {
    __syncthreads();  // all waves past phase-1 / prior-chunk Ks/Vs reads
#pragma unroll
    for (int rnd = 0; rnd < 2; ++rnd) {
      const int row = rnd * 32 + srow;
      const h8 kv = *(const h8*)(khb + (size_t)(kc * 64 + row) * 64 + ssl * 8);
      *(h8*)&Ks[row * 72 + ssl * 8] = kv;
      const h8 vv = *(const h8*)(Vbg + (size_t)row * S_ + kc * 64 + ssl * 8);
      *(h8*)&Vs[row * 72 + ssl * 8] = vv;
    }
    __syncthreads();

#pragma unroll
    for (int t = 0; t < 2; ++t) {
      // scores -> strip
#pragma unroll
      for (int kk = 0; kk < 4; ++kk) {
        const int krow = kk * 16 + li;
        const h8 bk0 = *(const h8*)&Ks[krow * 72 + g * 8];
        const h8 bk1 = *(const h8*)&Ks[krow * 72 + 32 + g * 8];
        const float bias = (float)sbias[kc * 64 + krow];
        f32x4 a = {0.f, 0.f, 0.f, 0.f};
        a = MFMA16(aq[t][0], bk0, a);
        a = MFMA16(aq[t][1], bk1, a);
#pragma unroll
        for (int r = 0; r < 4; ++r)
          Pw[(g * 4 + r) * 72 + krow] =
              (_Float16)(exp2f(fmaf(a[r], C_EXP2, bias)) * rl[t][r]);
      }
      // attn nt-stores: 4 insts, each 1 KB (4 rows x 256B contiguous)
#pragma unroll
      for (int rr = 0; rr < 4; ++rr) {
        const int row4 = rr * 4 + strow;
        const h4 p = *(const h4*)&Pw[row4 * 72 + stcol];
        f32x4 o;
        o[0] = (float)p[0]; o[1] = (float)p[1];
        o[2] = (float)p[2]; o[3] = (float)p[3];
        __builtin_nontemporal_store(
            o, (f32x4*)(ab + (size_t)(w * 32 + t * 16 + row4) * S_ + kc * 64 + stcol));
      }
      // PV from strip x staged V
#pragma unroll
      for (int ks = 0; ks < 2; ++ks) {
        const h8 pa = *(const h8*)&Pw[li * 72 + ks * 32 + g * 8];
#pragma unroll
        for (int u = 0; u < 4; ++u) {
          const h8 bf = *(const h8*)&Vs[(u * 16 + li) * 72 + ks * 32 + g * 8];
          acc[t][u] = MFMA16(pa, bf, acc[t][u]);
        }
      }
    }
  }

  // epilogue: ctx [B,S,1024] fp16
  _Float16* cb = ctx + ((size_t)bb * S_ + qt * 128 + w * 32 + g * 4) * DM_ + hh * 64 + li;
#pragma unroll
  for (int t = 0; t < 2; ++t)
#pragma unroll
    for (int u = 0; u < 4; ++u)
#pragma unroll
      for (int r = 0; r < 4; ++r)
        cb[(size_t)(t * 16 + r) * DM_ + u * 16] = (_Float16)acc[t][u][r];
}

// ---------------- residual + LayerNorm ----------------
__global__ __launch_bounds__(256)
void ln_kernel(const float* __restrict__ fc, const float* __restrict__ resid,
               const float* __restrict__ gamma, const float* __restrict__ beta,
               float* __restrict__ out) {
  __shared__ float red[8];
  const int row = blockIdx.x;
  const int t = threadIdx.x, w = t >> 6, lane = t & 63;
  const f32x4 xv = *(const f32x4*)(fc + (size_t)row * DM_ + t * 4);
  const f32x4 rv = *(const f32x4*)(resid + (size_t)row * DM_ + t * 4);
  float x0 = xv[0] + rv[0], x1 = xv[1] + rv[1], x2 = xv[2] + rv[2], x3 = xv[3] + rv[3];
  float s = x0 + x1 + x2 + x3;
#pragma unroll
  for (int off = 1; off < 64; off <<= 1) s += __shfl_xor(s, off);
  if (lane == 0) red[w] = s;
  __syncthreads();
  const float mu = (red[0] + red[1] + red[2] + red[3]) * (1.0f / (float)DM_);
  const float d0 = x0 - mu, d1 = x1 - mu, d2 = x2 - mu, d3 = x3 - mu;
  float sq = d0 * d0 + d1 * d1 + d2 * d2 + d3 * d3;
#pragma unroll
  for (int off = 1; off < 64; off <<= 1) sq += __shfl_xor(sq, off);
  if (lane == 0) red[4 + w] = sq;
  __syncthreads();
  const float inv = rsqrtf((red[4] + red[5] + red[6] + red[7]) * (1.0f / (float)DM_) + 1e-5f);
  const f32x4 gv = *(const f32x4*)(gamma + t * 4);
  const f32x4 bv = *(const f32x4*)(beta + t * 4);
  f32x4 o;
  o[0] = d0 * inv * gv[0] + bv[0];
  o[1] = d1 * inv * gv[1] + bv[1];
  o[2] = d2 * inv * gv[2] + bv[2];
  o[3] = d3 * inv * gv[3] + bv[3];
  *(f32x4*)(out + (size_t)row * DM_ + t * 4) = o;
}

// ---------------- launch ----------------
extern "C" void kernel_launch(void* const* d_in, const int* in_sizes, int n_in,
                              void* d_out, int out_size, void* d_ws, size_t ws_size,
                              hipStream_t stream) {
  const float* q = (const float*)d_in[0];
  const float* k = (const float*)d_in[1];
  const float* v = (const float*)d_in[2];
  const int* mask = (const int*)d_in[3];
  const float* wq = (const float*)d_in[4];
  const float* wk = (const float*)d_in[5];
  const float* wv = (const float*)d_in[6];
  const float* wfc = (const float*)d_in[7];
  const float* gamma = (const float*)d_in[8];
  const float* beta = (const float*)d_in[9];

  float* out0 = (float*)d_out;                  // [B,S,DM]
  float* attn = out0 + (size_t)B_ * S_ * DM_;   // [B,H,S,S] fp32

  // workspace layout — 64 MB total (fcp overlays qhp+khp, dead after attn)
  char* ws = (char*)d_ws;
  _Float16* qhp = (_Float16*)(ws + (0ull << 20));   // [B,H,S,64]   16 MB
  _Float16* khp = (_Float16*)(ws + (16ull << 20));  // [B,H,S,64]   16 MB
  _Float16* vtp = (_Float16*)(ws + (32ull << 20));  // [B,H,64,S]   16 MB
  _Float16* ctxp = (_Float16*)(ws + (48ull << 20)); // [B,S,1024]   16 MB
  float* fcp = (float*)(ws + (0ull << 20));         // [B*S,1024] fp32, 32 MB (overlay)

  gemm3_kernel<<<dim3(DM_ / 128, B_ * S_ / 128, 3), 256, 0, stream>>>(
      q, k, v, wq, wk, wv, qhp, khp, vtp);

  attn_kernel<<<dim3(1024), 256, 0, stream>>>(qhp, khp, vtp, mask, attn, ctxp);

  gemm_fc<<<dim3(DM_ / 128, B_ * S_ / 128), 256, 0, stream>>>(ctxp, wfc, fcp,
                                                              B_ * S_, DM_, DM_);

  ln_kernel<<<B_ * S_, 256, 0, stream>>>(fcp, q, gamma, beta, out0);
}